// Round 3
// baseline (1451.320 us; speedup 1.0000x reference)
//
#include <hip/hip_runtime.h>

#define Bz 8
#define Nn 2048
#define Cc 128
#define KK 16
#define WD 512
#define F2 64
#define FO 128
#define NP (Bz*Nn)
#define SQ2 1.41421356237309515f
#define HSTRIDE 136   // padded bf16 row stride (16B-aligned, conflict-friendly)
#define CAPMAX 192

// ws layout (float offsets)
#define GOFF   ((size_t)0)
#define BEOFF  ((size_t)1024)
#define LSOFF  ((size_t)2048)
#define HOFF   ((size_t)3072)
#define SQOFF  (HOFF + (size_t)NP*Cc)
#define A1OFF  (SQOFF + (size_t)NP)
#define ADOFF  (A1OFF + (size_t)NP*F2)
#define HXOFF  (ADOFF + (size_t)NP*Cc)
#define IXOFF  (HXOFF + (size_t)NP*Cc)
#define CNTOFF (IXOFF + (size_t)NP*KK)
// byte offsets for the u16 arrays
#define HIBYTES   ((CNTOFF + (size_t)NP) * 4)
#define CANDBYTES (HIBYTES + (size_t)NP*HSTRIDE*2)

typedef __attribute__((ext_vector_type(8))) short bf16x8;
typedef __attribute__((ext_vector_type(4))) float f32x4;

__device__ __forceinline__ unsigned short f2bf(float f) {
  unsigned u = __float_as_uint(f);
  unsigned r = (u + 0x7FFFu + ((u >> 16) & 1u)) >> 16;
  return (unsigned short)r;
}

// ---------------------------------------------------------------------------
// Kernel 1: per-batch FiLM vectors
__global__ __launch_bounds__(512) void k_pervec(const float* __restrict__ w,
    const float* __restrict__ Wg, const float* __restrict__ Wb,
    const float* __restrict__ Wls, const float* __restrict__ bls,
    float* __restrict__ ws) {
  __shared__ float red[3][4][Cc];
  const int b = blockIdx.x;
  const int c = threadIdx.x & 127, dc = threadIdx.x >> 7;
  const float* wr = w + b*WD;
  float ag = 0.f, ab = 0.f, al = 0.f;
  for (int d = dc*128; d < dc*128 + 128; ++d) {
    float wv = wr[d];
    ag = fmaf(wv, Wg[d*Cc + c], ag);
    ab = fmaf(wv, Wb[d*Cc + c], ab);
    al = fmaf(wv, Wls[d*Cc + c], al);
  }
  red[0][dc][c] = ag; red[1][dc][c] = ab; red[2][dc][c] = al;
  __syncthreads();
  if (dc == 0) {
    float sg = red[0][0][c] + red[0][1][c] + red[0][2][c] + red[0][3][c];
    float sb = red[1][0][c] + red[1][1][c] + red[1][2][c] + red[1][3][c];
    float sl = red[2][0][c] + red[2][1][c] + red[2][2][c] + red[2][3][c];
    ws[GOFF  + b*Cc + c] = 1.0f + sg;
    ws[BEOFF + b*Cc + c] = sb;
    ws[LSOFF + b*Cc + c] = sl + bls[c];
  }
}

// ---------------------------------------------------------------------------
// Kernel 2: h = LN(x)*g + beta, sq = sum(h*h), hi = bf16(h) (padded rows)
__global__ __launch_bounds__(64) void k_h(const float* __restrict__ x,
                                          float* __restrict__ ws,
                                          unsigned short* __restrict__ hi_g) {
  const int n = blockIdx.x;
  const int b = n >> 11;
  const int t = threadIdx.x;
  const float* xr = x + (size_t)n*Cc;
  float x0 = xr[t], x1 = xr[t + 64];
  float s = x0 + x1, ss = x0*x0 + x1*x1;
  #pragma unroll
  for (int m = 1; m < 64; m <<= 1) {
    s  += __shfl_xor(s,  m, 64);
    ss += __shfl_xor(ss, m, 64);
  }
  float mu  = s * (1.0f/128.0f);
  float var = ss * (1.0f/128.0f) - mu*mu;
  float rs  = rsqrtf(var + 1e-5f);
  float h0 = (x0 - mu)*rs*ws[GOFF + b*Cc + t]      + ws[BEOFF + b*Cc + t];
  float h1 = (x1 - mu)*rs*ws[GOFF + b*Cc + t + 64] + ws[BEOFF + b*Cc + t + 64];
  float* hr = ws + HOFF + (size_t)n*Cc;
  hr[t] = h0; hr[t + 64] = h1;
  hi_g[(size_t)n*HSTRIDE + t]      = f2bf(h0);
  hi_g[(size_t)n*HSTRIDE + t + 64] = f2bf(h1);
  float q = h0*h0 + h1*h1;
  #pragma unroll
  for (int m = 1; m < 64; m <<= 1) q += __shfl_xor(q, m, 64);
  if (t == 0) ws[SQOFF + n] = q;
}

// ---------------------------------------------------------------------------
// Kernel 3: precompute A1 = h@W1, Ad = h@Wx1[128:], hxb = h@Wx1[:128]-Ad+bx1
__global__ __launch_bounds__(128) void k_pre(const float* __restrict__ W1,
    const float* __restrict__ Wx1, const float* __restrict__ bx1,
    float* __restrict__ ws) {
  __shared__ float hs[4][Cc];
  const int t = threadIdx.x;
  const size_t row0 = (size_t)blockIdx.x * 4;
  const float* h = ws + HOFF;
  #pragma unroll
  for (int r = 0; r < 4; ++r) hs[r][t] = h[(row0 + r)*Cc + t];
  __syncthreads();
  float ad[4] = {0,0,0,0}, ac[4] = {0,0,0,0};
  for (int cp = 0; cp < Cc; ++cp) {
    float whi = Wx1[cp*FO + t];
    float wlo = Wx1[(Cc + cp)*FO + t];
    #pragma unroll
    for (int r = 0; r < 4; ++r) {
      float hv = hs[r][cp];
      ac[r] = fmaf(hv, whi, ac[r]);
      ad[r] = fmaf(hv, wlo, ad[r]);
    }
  }
  float bx = bx1[t];
  #pragma unroll
  for (int r = 0; r < 4; ++r) {
    ws[ADOFF + (row0 + r)*Cc + t] = ad[r];
    ws[HXOFF + (row0 + r)*Cc + t] = ac[r] - ad[r] + bx;
  }
  const int j = t & 63, rp = t >> 6;
  float a0 = 0.f, a1 = 0.f;
  for (int cp = 0; cp < Cc; ++cp) {
    float wv = W1[cp*F2 + j];
    a0 = fmaf(hs[rp][cp],     wv, a0);
    a1 = fmaf(hs[rp + 2][cp], wv, a1);
  }
  ws[A1OFF + (row0 + rp)*F2 + j]     = a0;
  ws[A1OFF + (row0 + rp + 2)*F2 + j] = a1;
}

// ---------------------------------------------------------------------------
// Kernel 4: MFMA approx distances + tau-filter compaction.
// Grid 256 (b x 32 i-tiles of 64 rows), 512 thr (8 waves).
// Wave (wi,wj): i-rows 32wi..+32, j-cols 32wj..+32 of each 64x128 tile.
// jt=0 doubles as the tau sample (6th smallest of 128 per row).
__global__ __launch_bounds__(512, 1) void k_filter(float* __restrict__ ws,
    const unsigned short* __restrict__ hi_g, unsigned short* __restrict__ cand,
    int* __restrict__ cnt_g, int CAP) {
  __shared__ unsigned short hiA[64*HSTRIDE];   // 17408 B
  __shared__ float smB[8704];                  // hB u16[128*136] / dstage f32[64*132]
  __shared__ float sqA[64], sqB[128], tauS[64];
  __shared__ int cnt[64];
  unsigned short* hB = (unsigned short*)smB;
  float* dstage = smB;                         // stride 132
  const int t = threadIdx.x;
  const int b = blockIdx.x >> 5;
  const int i0 = (blockIdx.x & 31) << 6;
  const int wave = t >> 6, lane = t & 63;
  const int wi = wave & 1, wj = wave >> 1;     // wj 0..3
  const int l15 = lane & 15, l4 = lane >> 4;
  const float* __restrict__ sq = ws + SQOFF + (size_t)b*Nn;
  const unsigned short* __restrict__ hib = hi_g + (size_t)b*Nn*HSTRIDE;

  { // load hiA: 64 rows x 128 cols (pad never read)
    int r = t >> 3, o = (t & 7) * 16;
    *(bf16x8*)&hiA[r*HSTRIDE + o]     = *(const bf16x8*)&hib[(size_t)(i0 + r)*HSTRIDE + o];
    *(bf16x8*)&hiA[r*HSTRIDE + o + 8] = *(const bf16x8*)&hib[(size_t)(i0 + r)*HSTRIDE + o + 8];
  }
  if (t < 64) { sqA[t] = sq[i0 + t]; cnt[t] = 0; }

  for (int jt = 0; jt < 16; ++jt) {
    const int j0 = jt << 7;
    __syncthreads();   // smB / sqB free (prev filter done)
    { // stage hB: 128 rows x 128 cols
      int r = t >> 2, o = (t & 3) * 32;
      #pragma unroll
      for (int q = 0; q < 4; ++q)
        *(bf16x8*)&hB[r*HSTRIDE + o + q*8] =
            *(const bf16x8*)&hib[(size_t)(j0 + r)*HSTRIDE + o + q*8];
    }
    if (t < 128) sqB[t] = sq[j0 + t];
    __syncthreads();

    f32x4 acc00 = {0,0,0,0}, acc01 = {0,0,0,0}, acc10 = {0,0,0,0}, acc11 = {0,0,0,0};
    #pragma unroll
    for (int kb = 0; kb < 4; ++kb) {
      const int cbase = kb*32 + l4*8;
      bf16x8 a0 = *(const bf16x8*)&hiA[(32*wi      + l15)*HSTRIDE + cbase];
      bf16x8 a1 = *(const bf16x8*)&hiA[(32*wi + 16 + l15)*HSTRIDE + cbase];
      bf16x8 b0 = *(const bf16x8*)&hB [(32*wj      + l15)*HSTRIDE + cbase];
      bf16x8 b1 = *(const bf16x8*)&hB [(32*wj + 16 + l15)*HSTRIDE + cbase];
      acc00 = __builtin_amdgcn_mfma_f32_16x16x32_bf16(a0, b0, acc00, 0, 0, 0);
      acc01 = __builtin_amdgcn_mfma_f32_16x16x32_bf16(a0, b1, acc01, 0, 0, 0);
      acc10 = __builtin_amdgcn_mfma_f32_16x16x32_bf16(a1, b0, acc10, 0, 0, 0);
      acc11 = __builtin_amdgcn_mfma_f32_16x16x32_bf16(a1, b1, acc11, 0, 0, 0);
    }

    if (jt == 0) {
      __syncthreads();   // all waves done reading hB -> reuse as dstage
      #pragma unroll
      for (int ib = 0; ib < 2; ++ib)
        #pragma unroll
        for (int jb = 0; jb < 2; ++jb) {
          const f32x4 a = ib ? (jb ? acc11 : acc10) : (jb ? acc01 : acc00);
          #pragma unroll
          for (int r = 0; r < 4; ++r) {
            int il = 32*wi + 16*ib + l4*4 + r;
            int jl = 32*wj + 16*jb + l15;
            dstage[il*132 + jl] = sqA[il] + sqB[jl] - 2.f*a[r];
          }
        }
      __syncthreads();
      { // tau[row] = 6th smallest of 128 (lex (d, id) for exact removal)
        int row = wave*8;
        for (int rr = 0; rr < 8; ++rr, ++row) {
          float v0 = dstage[row*132 + lane];
          float v1 = dstage[row*132 + 64 + lane];
          float t6 = 0.f;
          #pragma unroll
          for (int r6 = 0; r6 < 6; ++r6) {
            float mv; int mi;
            if (v0 <= v1) { mv = v0; mi = lane; } else { mv = v1; mi = 64 + lane; }
            #pragma unroll
            for (int s2 = 1; s2 < 64; s2 <<= 1) {
              float ov = __shfl_xor(mv, s2, 64);
              int   oi = __shfl_xor(mi, s2, 64);
              if (ov < mv || (ov == mv && oi < mi)) { mv = ov; mi = oi; }
            }
            t6 = mv;
            if (mi == lane)      v0 = 3.0e38f;
            if (mi == 64 + lane) v1 = 3.0e38f;
          }
          if (lane == 0) tauS[row] = t6;
        }
      }
      __syncthreads();
      { // filter jt0 from dstage
        int row = t >> 3, cb = (t & 7) * 16;
        float tv = tauS[row];
        size_t rg = (size_t)(b*Nn + i0 + row);
        #pragma unroll 1
        for (int c = 0; c < 16; ++c) {
          float dv = dstage[row*132 + cb + c];
          if (dv < tv) {
            int pos = atomicAdd(&cnt[row], 1);
            if (pos < CAP) cand[rg*CAPMAX + pos] = (unsigned short)(cb + c);
          }
        }
      }
    } else {
      // filter from acc regs
      #pragma unroll
      for (int ib = 0; ib < 2; ++ib)
        #pragma unroll
        for (int jb = 0; jb < 2; ++jb) {
          const f32x4 a = ib ? (jb ? acc11 : acc10) : (jb ? acc01 : acc00);
          #pragma unroll
          for (int r = 0; r < 4; ++r) {
            int il = 32*wi + 16*ib + l4*4 + r;
            int jl = 32*wj + 16*jb + l15;
            float dv = sqA[il] + sqB[jl] - 2.f*a[r];
            if (dv < tauS[il]) {
              int pos = atomicAdd(&cnt[il], 1);
              if (pos < CAP)
                cand[(size_t)(b*Nn + i0 + il)*CAPMAX + pos] = (unsigned short)(j0 + jl);
            }
          }
        }
    }
  }
  __syncthreads();
  if (t < 64) cnt_g[b*Nn + i0 + t] = cnt[t];
}

// ---------------------------------------------------------------------------
// Kernel 5: exact fp32 refine: distances for <=CAP candidates, rank-by-count.
// Rank 0 = self (d=0); ranks 1..16 -> idx (lex (d,j) tie-break matches top_k).
__global__ __launch_bounds__(256) void k_refine(float* __restrict__ ws,
    const unsigned short* __restrict__ cand, const int* __restrict__ cnt_g,
    int CAP) {
  __shared__ float hi_s[4][Cc];
  __shared__ float dsh[4][CAPMAX];
  __shared__ unsigned short cjs[4][CAPMAX];
  const int wave = threadIdx.x >> 6, lane = threadIdx.x & 63;
  const int row = blockIdx.x*4 + wave;
  const int b = row >> 11;
  const float* __restrict__ h = ws + HOFF;
  int c_ = cnt_g[row];
  int cm = (c_ < 17 || c_ > CAP) ? 0 : c_;
  hi_s[wave][lane]      = h[(size_t)row*Cc + lane];
  hi_s[wave][lane + 64] = h[(size_t)row*Cc + lane + 64];
  for (int cc = lane; cc < cm; cc += 64)
    cjs[wave][cc] = cand[(size_t)row*CAPMAX + cc];
  __syncthreads();
  for (int cc = lane; cc < cm; cc += 64) {
    const float* hj = h + (size_t)(b*Nn + cjs[wave][cc])*Cc;
    float d = 0.f;
    #pragma unroll
    for (int q = 0; q < 32; ++q) {
      float4 a = *(const float4*)&hi_s[wave][q*4];
      float4 c4 = *(const float4*)(hj + q*4);
      float e0 = a.x - c4.x, e1 = a.y - c4.y, e2 = a.z - c4.z, e3 = a.w - c4.w;
      d = fmaf(e0, e0, d); d = fmaf(e1, e1, d);
      d = fmaf(e2, e2, d); d = fmaf(e3, e3, d);
    }
    dsh[wave][cc] = d;
  }
  __syncthreads();
  int* op = (int*)(ws + IXOFF) + (size_t)row*KK;
  for (int cc = lane; cc < cm; cc += 64) {
    float dc = dsh[wave][cc];
    int jc = cjs[wave][cc];
    int rank = 0;
    #pragma unroll 1
    for (int m = 0; m < cm; ++m) {
      float dm = dsh[wave][m];
      int jm = cjs[wave][m];
      rank += (dm < dc || (dm == dc && jm < jc)) ? 1 : 0;
    }
    if (rank >= 1 && rank <= 16) op[rank - 1] = b*Nn + jc;
  }
}

// ---------------------------------------------------------------------------
// Kernel 6: fallback exact full-scan for flagged rows (cnt<17 or >CAP).
__global__ __launch_bounds__(256) void k_fb(float* __restrict__ ws,
    const int* __restrict__ cnt_g, int CAP) {
  const int wave = threadIdx.x >> 6, lane = threadIdx.x & 63;
  const int row = blockIdx.x*4 + wave;
  int c_ = cnt_g[row];
  if (c_ >= 17 && c_ <= CAP) return;   // wave-uniform; no LDS/syncs in kernel
  const int b = row >> 11;
  const float* __restrict__ h = ws + HOFF + (size_t)b*Nn*Cc;
  const float* __restrict__ hi = h + (size_t)(row & (Nn-1))*Cc;
  float td[17]; int tj[17];
  #pragma unroll
  for (int s = 0; s < 17; ++s) { td[s] = 3.0e38f; tj[s] = 0x7FFFFFFF; }
  float cmax = 3.0e38f; int cjm = 0x7FFFFFFF, cpos = 0;
  for (int m = 0; m < 32; ++m) {
    int j = lane + m*64;
    const float* hj = h + (size_t)j*Cc;
    float d = 0.f;
    #pragma unroll
    for (int q = 0; q < 32; ++q) {
      float4 a = *(const float4*)(hi + q*4);
      float4 c4 = *(const float4*)(hj + q*4);
      float e0 = a.x - c4.x, e1 = a.y - c4.y, e2 = a.z - c4.z, e3 = a.w - c4.w;
      d = fmaf(e0, e0, d); d = fmaf(e1, e1, d);
      d = fmaf(e2, e2, d); d = fmaf(e3, e3, d);
    }
    if (d < cmax || (d == cmax && j < cjm)) {
      #pragma unroll
      for (int s = 0; s < 17; ++s) {
        bool r = (s == cpos);
        td[s] = r ? d : td[s];
        tj[s] = r ? j : tj[s];
      }
      cmax = td[0]; cjm = tj[0]; cpos = 0;
      #pragma unroll
      for (int s = 1; s < 17; ++s)
        if (td[s] > cmax || (td[s] == cmax && tj[s] > cjm)) {
          cmax = td[s]; cjm = tj[s]; cpos = s;
        }
    }
  }
  // 17 extraction rounds across lanes (lex order), round 0 = self
  int* op = (int*)(ws + IXOFF) + (size_t)row*KK;
  #pragma unroll 1
  for (int r17 = 0; r17 < 17; ++r17) {
    float mv = td[0]; int mj = tj[0], mp = 0;
    #pragma unroll
    for (int s = 1; s < 17; ++s)
      if (td[s] < mv || (td[s] == mv && tj[s] < mj)) { mv = td[s]; mj = tj[s]; mp = s; }
    #pragma unroll
    for (int s2 = 1; s2 < 64; s2 <<= 1) {
      float ov = __shfl_xor(mv, s2, 64);
      int   oj = __shfl_xor(mj, s2, 64);
      if (ov < mv || (ov == mv && oj < mj)) { mv = ov; mj = oj; }
    }
    if (tj[mp] == mj) { td[mp] = 3.0e38f; tj[mp] = 0x7FFFFFFF; }  // owner removes
    if (r17 >= 1 && lane == 0) op[r17 - 1] = b*Nn + mj;
  }
}

// ---------------------------------------------------------------------------
// Kernel 7: fused per-point MLP + softmax + aggregate + residual.
__global__ __launch_bounds__(64) void k_mlp(
    const float* __restrict__ b1v, const float* __restrict__ W2,
    const float* __restrict__ Wx2, const float* __restrict__ bx2,
    const float* __restrict__ x, float* __restrict__ out,
    float* __restrict__ ws) {
  __shared__ float hw_s[64][20];
  __shared__ float hx_s[128][20];
  __shared__ int mk[16];
  const int n = blockIdx.x;
  const int b = n >> 11;
  const int t = threadIdx.x;
  const int* __restrict__ ip = (const int*)(ws + IXOFF) + (size_t)n*KK;
  if (t < 16) mk[t] = ip[t];
  __syncthreads();
  {
    const float* A1 = ws + A1OFF;
    float a1n = A1[(size_t)n*F2 + t];
    float bb  = b1v[t];
    #pragma unroll
    for (int k = 0; k < 16; ++k) {
      float v = A1[(size_t)mk[k]*F2 + t] - a1n + bb;
      v = (v > 0.f ? v : 0.2f*v) * SQ2;
      hw_s[t][k] = v;
    }
  }
  __syncthreads();
  float wlA[16], wlB[16];
  #pragma unroll
  for (int k = 0; k < 16; ++k) { wlA[k] = 0.f; wlB[k] = 0.f; }
  for (int j = 0; j < 64; ++j) {
    float w2a = W2[j*FO + t];
    float w2b = W2[j*FO + t + 64];
    const float4* hp = (const float4*)(&hw_s[j][0]);
    float4 q0 = hp[0], q1 = hp[1], q2 = hp[2], q3 = hp[3];
    float hv[16] = {q0.x,q0.y,q0.z,q0.w, q1.x,q1.y,q1.z,q1.w,
                    q2.x,q2.y,q2.z,q2.w, q3.x,q3.y,q3.z,q3.w};
    #pragma unroll
    for (int k = 0; k < 16; ++k) {
      wlA[k] = fmaf(hv[k], w2a, wlA[k]);
      wlB[k] = fmaf(hv[k], w2b, wlB[k]);
    }
  }
  {
    float mA = wlA[0], mB = wlB[0];
    #pragma unroll
    for (int k = 1; k < 16; ++k) { mA = fmaxf(mA, wlA[k]); mB = fmaxf(mB, wlB[k]); }
    float sA = 0.f, sB = 0.f;
    #pragma unroll
    for (int k = 0; k < 16; ++k) {
      wlA[k] = __expf(wlA[k] - mA); sA += wlA[k];
      wlB[k] = __expf(wlB[k] - mB); sB += wlB[k];
    }
    float rA = 1.0f/sA, rB = 1.0f/sB;
    #pragma unroll
    for (int k = 0; k < 16; ++k) { wlA[k] *= rA; wlB[k] *= rB; }
  }
  {
    const float* Ad = ws + ADOFF;
    float hbA = ws[HXOFF + (size_t)n*Cc + t];
    float hbB = ws[HXOFF + (size_t)n*Cc + t + 64];
    #pragma unroll
    for (int k = 0; k < 16; ++k) {
      size_t mo = (size_t)mk[k]*Cc;
      float vA = hbA + Ad[mo + t];
      float vB = hbB + Ad[mo + t + 64];
      vA = (vA > 0.f ? vA : 0.2f*vA) * SQ2;
      vB = (vB > 0.f ? vB : 0.2f*vB) * SQ2;
      hx_s[t][k]      = vA;
      hx_s[t + 64][k] = vB;
    }
  }
  __syncthreads();
  float xeA[16], xeB[16];
  #pragma unroll
  for (int k = 0; k < 16; ++k) { xeA[k] = 0.f; xeB[k] = 0.f; }
  for (int j = 0; j < 128; ++j) {
    float wxa = Wx2[j*FO + t];
    float wxb = Wx2[j*FO + t + 64];
    const float4* hp = (const float4*)(&hx_s[j][0]);
    float4 q0 = hp[0], q1 = hp[1], q2 = hp[2], q3 = hp[3];
    float hv[16] = {q0.x,q0.y,q0.z,q0.w, q1.x,q1.y,q1.z,q1.w,
                    q2.x,q2.y,q2.z,q2.w, q3.x,q3.y,q3.z,q3.w};
    #pragma unroll
    for (int k = 0; k < 16; ++k) {
      xeA[k] = fmaf(hv[k], wxa, xeA[k]);
      xeB[k] = fmaf(hv[k], wxb, xeB[k]);
    }
  }
  float bxa = bx2[t], bxb = bx2[t + 64];
  float aggA = 0.f, aggB = 0.f;
  #pragma unroll
  for (int k = 0; k < 16; ++k) {
    aggA = fmaf(xeA[k] + bxa, wlA[k], aggA);
    aggB = fmaf(xeB[k] + bxb, wlB[k], aggB);
  }
  float lsA = ws[LSOFF + b*Cc + t];
  float lsB = ws[LSOFF + b*Cc + t + 64];
  size_t xo = (size_t)n*Cc;
  out[xo + t]      = fmaf(aggA, lsA, x[xo + t]);
  out[xo + t + 64] = fmaf(aggB, lsB, x[xo + t + 64]);
}

// ---------------------------------------------------------------------------
extern "C" void kernel_launch(void* const* d_in, const int* in_sizes, int n_in,
                              void* d_out, int out_size, void* d_ws, size_t ws_size,
                              hipStream_t stream) {
  const float* x   = (const float*)d_in[0];
  const float* w   = (const float*)d_in[1];
  const float* Wg  = (const float*)d_in[2];
  const float* Wb  = (const float*)d_in[3];
  const float* W1  = (const float*)d_in[4];
  const float* b1  = (const float*)d_in[5];
  const float* W2  = (const float*)d_in[6];
  const float* Wx1 = (const float*)d_in[8];
  const float* bx1 = (const float*)d_in[9];
  const float* Wx2 = (const float*)d_in[10];
  const float* bx2 = (const float*)d_in[11];
  const float* Wls = (const float*)d_in[12];
  const float* bls = (const float*)d_in[13];
  float* out = (float*)d_out;
  float* ws  = (float*)d_ws;
  unsigned short* hi_g = (unsigned short*)((char*)d_ws + HIBYTES);
  unsigned short* cand = (unsigned short*)((char*)d_ws + CANDBYTES);
  int* cnt_g = (int*)(ws + CNTOFF);

  // cand rows are CAPMAX-strided; usable CAP adapts to the scratch we have.
  int CAP = 0;
  if (ws_size > CANDBYTES) {
    size_t c = (ws_size - CANDBYTES) / ((size_t)NP * 2);
    CAP = (c >= CAPMAX) ? CAPMAX : (int)c;
  }

  k_pervec<<<Bz, 512, 0, stream>>>(w, Wg, Wb, Wls, bls, ws);
  k_h<<<NP, 64, 0, stream>>>(x, ws, hi_g);
  k_pre<<<NP/4, 128, 0, stream>>>(W1, Wx1, bx1, ws);
  k_filter<<<256, 512, 0, stream>>>(ws, hi_g, cand, cnt_g, CAP);
  k_refine<<<NP/4, 256, 0, stream>>>(ws, cand, cnt_g, CAP);
  k_fb<<<NP/4, 256, 0, stream>>>(ws, cnt_g, CAP);
  k_mlp<<<NP, 64, 0, stream>>>(b1, W2, Wx2, bx2, x, out, ws);
}